// Round 1
// baseline (1261.743 us; speedup 1.0000x reference)
//
#include <hip/hip_runtime.h>
#include <math.h>

#define NB 65536
#define TRS 225  // per-batch-element trace row stride in LDS (224 + 1 pad -> banks (b+d)%32, 2-way = free)

// task t = l*3+p; src = FANO[l][p], par = FANO[l][(p+1)%3]
static __device__ const int T_SRC[21] = {0,1,2, 0,3,4, 0,5,6, 1,3,5, 1,4,6, 2,3,6, 2,4,5};
static __device__ const int T_PAR[21] = {1,2,0, 3,4,0, 5,6,0, 3,5,1, 4,6,1, 3,6,2, 4,5,2};

__device__ __forceinline__ float sigf(float x) { return 1.f / (1.f + expf(-x)); }

__global__ __launch_bounds__(256, 2)
void ccc_fused(const float* __restrict__ z,
               const float* __restrict__ gen_W1, const float* __restrict__ gen_b1,
               const float* __restrict__ gen_g,  const float* __restrict__ gen_be,
               const float* __restrict__ gen_W2, const float* __restrict__ gen_b2,
               const float* __restrict__ cf_W1,  const float* __restrict__ cf_b1,
               const float* __restrict__ cf_W2,  const float* __restrict__ cf_b2,
               const float* __restrict__ g_W,    const float* __restrict__ g_b,
               const float* __restrict__ c_W1,   const float* __restrict__ c_b1,
               const float* __restrict__ c_g,    const float* __restrict__ c_be,
               const float* __restrict__ c_W2,   const float* __restrict__ c_b2,
               float* __restrict__ out)
{
    __shared__ float tr[64 * TRS];     // normalized traces, flat [b_local][c*32+d]
    __shared__ float conf_s[7][64];
    __shared__ float gate_s[7][64];

    const int lane = threadIdx.x & 63;
    const int wave = __builtin_amdgcn_readfirstlane((int)(threadIdx.x >> 6)); // scalar -> uniform ctrl flow
    const int b    = blockIdx.x * 64 + lane;

    float* trb = &tr[lane * TRS];

    // ================= Phase A: per-colony trace gen + conf (wave w -> colonies w, w+4) =================
    for (int c = wave; c < 7; c += 4) {
        float zv[14];
        {
            const float* zp = z + ((size_t)b * 7 + (size_t)c) * 14;
            #pragma unroll
            for (int i = 0; i < 7; ++i) {
                float2 u = *(const float2*)(zp + 2 * i);
                zv[2*i] = u.x; zv[2*i+1] = u.y;
            }
        }
        // h = z @ gen_W1[c] + gen_b1[c]   (weights wave-uniform -> s_load)
        float h[64];
        {
            const float* bp = gen_b1 + c * 64;
            #pragma unroll
            for (int j = 0; j < 64; ++j) h[j] = bp[j];
            const float* W = gen_W1 + c * 14 * 64;
            for (int i = 0; i < 14; ++i) {
                const float zi = zv[i];
                const float* w = W + i * 64;
                #pragma unroll
                for (int j = 0; j < 64; ++j) h[j] = fmaf(zi, w[j], h[j]);
            }
        }
        // LayerNorm (thread-local, biased var, eps 1e-5)
        {
            float m = 0.f;
            #pragma unroll
            for (int j = 0; j < 64; ++j) m += h[j];
            m *= (1.f / 64.f);
            float v = 0.f;
            #pragma unroll
            for (int j = 0; j < 64; ++j) { float d = h[j] - m; v = fmaf(d, d, v); }
            v *= (1.f / 64.f);
            const float rs = 1.f / sqrtf(v + 1e-5f);
            const float* gp = gen_g  + c * 64;
            const float* bp = gen_be + c * 64;
            #pragma unroll
            for (int j = 0; j < 64; ++j) h[j] = (h[j] - m) * rs * gp[j] + bp[j];
        }
        // colony-specific activation (c wave-uniform -> no divergence)
        switch (c) {
            case 0:
                #pragma unroll
                for (int j = 0; j < 64; ++j) h[j] = fmaxf(h[j], 0.f);
                break;
            case 1:
                #pragma unroll
                for (int j = 0; j < 64; ++j) h[j] = tanhf(h[j]);
                break;
            case 2:  // exact gelu
                #pragma unroll
                for (int j = 0; j < 64; ++j) h[j] = 0.5f * h[j] * (1.f + erff(h[j] * 0.70710678118654752f));
                break;
            case 3:  // silu
                #pragma unroll
                for (int j = 0; j < 64; ++j) h[j] = h[j] * sigf(h[j]);
                break;
            case 4:  // softplus = max(x,0) + log1p(exp(-|x|))
                #pragma unroll
                for (int j = 0; j < 64; ++j) h[j] = fmaxf(h[j], 0.f) + log1pf(expf(-fabsf(h[j])));
                break;
            case 5:
                #pragma unroll
                for (int j = 0; j < 64; ++j) h[j] = sigf(h[j]);
                break;
            default:  // clip(-1,1)
                #pragma unroll
                for (int j = 0; j < 64; ++j) h[j] = fminf(fmaxf(h[j], -1.f), 1.f);
                break;
        }
        // traces = a @ gen_W2[c] + gen_b2[c], then l2norm, store to LDS
        {
            float t[32];
            const float* bp = gen_b2 + c * 32;
            #pragma unroll
            for (int d = 0; d < 32; ++d) t[d] = bp[d];
            const float* W = gen_W2 + c * 64 * 32;
            #pragma unroll
            for (int j = 0; j < 64; ++j) {
                const float a = h[j];
                const float* w = W + j * 32;
                #pragma unroll
                for (int d = 0; d < 32; ++d) t[d] = fmaf(a, w[d], t[d]);
            }
            float s = 0.f;
            #pragma unroll
            for (int d = 0; d < 32; ++d) s = fmaf(t[d], t[d], s);
            const float inv = 1.f / fmaxf(sqrtf(s), 1e-12f);
            #pragma unroll
            for (int d = 0; d < 32; ++d) trb[c * 32 + d] = t[d] * inv;
        }
        // confidence head
        {
            float hc[32];
            const float* bp = cf_b1 + c * 32;
            #pragma unroll
            for (int k = 0; k < 32; ++k) hc[k] = bp[k];
            const float* W = cf_W1 + c * 14 * 32;
            for (int i = 0; i < 14; ++i) {
                const float zi = zv[i];
                const float* w = W + i * 32;
                #pragma unroll
                for (int k = 0; k < 32; ++k) hc[k] = fmaf(zi, w[k], hc[k]);
            }
            float cl = cf_b2[c];
            const float* w2 = cf_W2 + c * 32;
            #pragma unroll
            for (int k = 0; k < 32; ++k) cl = fmaf(fmaxf(hc[k], 0.f), w2[k], cl);
            conf_s[c][lane] = sigf(cl);
        }
    }
    __syncthreads();

    // ================= Phase B: line gates (wave w -> lines w, w+4) =================
    for (int l = wave; l < 7; l += 4) {
        float gl = g_b[l];
        #pragma unroll 8
        for (int k = 0; k < 224; ++k)
            gl = fmaf(trb[k], g_W[k * 7 + l], gl);
        gate_s[l][lane] = sigf(gl);
    }
    __syncthreads();

    // ================= Phase C: composers (wave w -> tasks w, w+4, ...) =================
    for (int t = wave; t < 21; t += 4) {
        const int l   = __builtin_amdgcn_readfirstlane(t / 3);
        const int src = T_SRC[t];
        const int par = T_PAR[t];

        float ch[64];
        {
            const float* bp = c_b1 + l * 64;
            #pragma unroll
            for (int j = 0; j < 64; ++j) ch[j] = bp[j];
            const float* W  = c_W1 + l * 64 * 64;
            const float* ts = trb + src * 32;
            for (int i = 0; i < 32; ++i) {
                const float v = ts[i];
                const float* w = W + i * 64;
                #pragma unroll
                for (int j = 0; j < 64; ++j) ch[j] = fmaf(v, w[j], ch[j]);
            }
            const float* tp = trb + par * 32;
            for (int i = 0; i < 32; ++i) {
                const float v = tp[i];
                const float* w = W + (32 + i) * 64;
                #pragma unroll
                for (int j = 0; j < 64; ++j) ch[j] = fmaf(v, w[j], ch[j]);
            }
        }
        // LN -> relu
        {
            float m = 0.f;
            #pragma unroll
            for (int j = 0; j < 64; ++j) m += ch[j];
            m *= (1.f / 64.f);
            float v = 0.f;
            #pragma unroll
            for (int j = 0; j < 64; ++j) { float d = ch[j] - m; v = fmaf(d, d, v); }
            v *= (1.f / 64.f);
            const float rs = 1.f / sqrtf(v + 1e-5f);
            const float* gp = c_g  + l * 64;
            const float* bp = c_be + l * 64;
            #pragma unroll
            for (int j = 0; j < 64; ++j) ch[j] = fmaxf((ch[j] - m) * rs * gp[j] + bp[j], 0.f);
        }
        // cv = a @ c_W2[l] + c_b2[l]
        float cv[32];
        {
            const float* bp = c_b2 + l * 32;
            #pragma unroll
            for (int d = 0; d < 32; ++d) cv[d] = bp[d];
            const float* W2 = c_W2 + l * 64 * 32;
            #pragma unroll
            for (int j = 0; j < 64; ++j) {
                const float a = ch[j];
                const float* w = W2 + j * 32;
                #pragma unroll
                for (int d = 0; d < 32; ++d) cv[d] = fmaf(a, w[d], cv[d]);
            }
        }
        // l2norm, gate scale/threshold, write
        float s = 0.f;
        #pragma unroll
        for (int d = 0; d < 32; ++d) s = fmaf(cv[d], cv[d], s);
        const float inv  = 1.f / fmaxf(sqrtf(s), 1e-12f);
        const float gate = gate_s[l][lane];
        const bool  act  = (gate >= 0.3f);
        const float scale = act ? gate * inv : 0.f;
        const float cc    = act ? conf_s[src][lane] * conf_s[par][lane] * gate : 0.f;

        float* op = out + (size_t)b * 672 + (size_t)t * 32;
        #pragma unroll
        for (int d = 0; d < 32; d += 4) {
            float4 o;
            o.x = cv[d+0] * scale; o.y = cv[d+1] * scale;
            o.z = cv[d+2] * scale; o.w = cv[d+3] * scale;
            *(float4*)(op + d) = o;
        }
        out[(size_t)NB * 672 + (size_t)b * 21 + t] = cc;
    }
}

extern "C" void kernel_launch(void* const* d_in, const int* in_sizes, int n_in,
                              void* d_out, int out_size, void* d_ws, size_t ws_size,
                              hipStream_t stream) {
    const float* z      = (const float*)d_in[0];
    const float* gen_W1 = (const float*)d_in[1];
    const float* gen_b1 = (const float*)d_in[2];
    const float* gen_g  = (const float*)d_in[3];
    const float* gen_be = (const float*)d_in[4];
    const float* gen_W2 = (const float*)d_in[5];
    const float* gen_b2 = (const float*)d_in[6];
    const float* cf_W1  = (const float*)d_in[7];
    const float* cf_b1  = (const float*)d_in[8];
    const float* cf_W2  = (const float*)d_in[9];
    const float* cf_b2  = (const float*)d_in[10];
    const float* g_W    = (const float*)d_in[11];
    const float* g_b    = (const float*)d_in[12];
    const float* c_W1   = (const float*)d_in[13];
    const float* c_b1   = (const float*)d_in[14];
    const float* c_g    = (const float*)d_in[15];
    const float* c_be   = (const float*)d_in[16];
    const float* c_W2   = (const float*)d_in[17];
    const float* c_b2   = (const float*)d_in[18];

    ccc_fused<<<dim3(NB / 64), dim3(256), 0, stream>>>(
        z, gen_W1, gen_b1, gen_g, gen_be, gen_W2, gen_b2,
        cf_W1, cf_b1, cf_W2, cf_b2, g_W, g_b,
        c_W1, c_b1, c_g, c_be, c_W2, c_b2,
        (float*)d_out);
}

// Round 2
// 745.884 us; speedup vs baseline: 1.6916x; 1.6916x over previous
//
#include <hip/hip_runtime.h>
#include <math.h>

#define NB 65536

// workspace layout (floats):
//   traces: [7][NB][32]  at 0
//   conf:   [7][NB]      at TR_WS
//   gates:  [7][NB]      at CF_WS
#define TR_WS ((size_t)7 * NB * 32)
#define CF_WS (TR_WS + (size_t)7 * NB)

// task t = l*3+p; src = FANO[l][p], par = FANO[l][(p+1)%3]
static __device__ const int T_SRC[21] = {0,1,2, 0,3,4, 0,5,6, 1,3,5, 1,4,6, 2,3,6, 2,4,5};
static __device__ const int T_PAR[21] = {1,2,0, 3,4,0, 5,6,0, 3,5,1, 4,6,1, 3,6,2, 4,5,2};

__device__ __forceinline__ float sigf(float x) { return 1.f / (1.f + expf(-x)); }

// ============ Kernel A: per-colony trace generator + confidence ============
// grid = 7*256 blocks; block handles colony c = blockIdx>>8 for 256 batch elems.
__global__ __launch_bounds__(256, 4)
void colA(const float* __restrict__ z,
          const float* __restrict__ gen_W1, const float* __restrict__ gen_b1,
          const float* __restrict__ gen_g,  const float* __restrict__ gen_be,
          const float* __restrict__ gen_W2, const float* __restrict__ gen_b2,
          const float* __restrict__ cf_W1,  const float* __restrict__ cf_b1,
          const float* __restrict__ cf_W2,  const float* __restrict__ cf_b2,
          float* __restrict__ ws)
{
    const int c = blockIdx.x >> 8;                       // uniform per block
    const int b = ((blockIdx.x & 255) << 8) + threadIdx.x;

    float zv[14];
    {
        const float* zp = z + ((size_t)b * 7 + (size_t)c) * 14;
        #pragma unroll
        for (int i = 0; i < 7; ++i) {
            float2 u = *(const float2*)(zp + 2 * i);
            zv[2*i] = u.x; zv[2*i+1] = u.y;
        }
    }

    // ---- confidence head first (keeps peak VGPR low: zv + hc only) ----
    {
        float hc[32];
        const float* bp = cf_b1 + c * 32;
        #pragma unroll
        for (int k = 0; k < 32; ++k) hc[k] = bp[k];
        const float* W = cf_W1 + c * 14 * 32;
        for (int i = 0; i < 14; ++i) {
            const float zi = zv[i];
            const float* w = W + i * 32;
            #pragma unroll
            for (int k = 0; k < 32; ++k) hc[k] = fmaf(zi, w[k], hc[k]);
        }
        float cl = cf_b2[c];
        const float* w2 = cf_W2 + c * 32;
        #pragma unroll
        for (int k = 0; k < 32; ++k) cl = fmaf(fmaxf(hc[k], 0.f), w2[k], cl);
        ws[TR_WS + (size_t)c * NB + b] = sigf(cl);
    }

    // ---- h = z @ gen_W1[c] + b1 ----
    float h[64];
    {
        const float* bp = gen_b1 + c * 64;
        #pragma unroll
        for (int j = 0; j < 64; ++j) h[j] = bp[j];
        const float* W = gen_W1 + c * 14 * 64;
        for (int i = 0; i < 14; ++i) {
            const float zi = zv[i];
            const float* w = W + i * 64;
            #pragma unroll
            for (int j = 0; j < 64; ++j) h[j] = fmaf(zi, w[j], h[j]);
        }
    }
    // ---- LayerNorm ----
    {
        float m = 0.f;
        #pragma unroll
        for (int j = 0; j < 64; ++j) m += h[j];
        m *= (1.f / 64.f);
        float v = 0.f;
        #pragma unroll
        for (int j = 0; j < 64; ++j) { float d = h[j] - m; v = fmaf(d, d, v); }
        v *= (1.f / 64.f);
        const float rs = 1.f / sqrtf(v + 1e-5f);
        const float* gp = gen_g  + c * 64;
        const float* bp = gen_be + c * 64;
        #pragma unroll
        for (int j = 0; j < 64; ++j) h[j] = (h[j] - m) * rs * gp[j] + bp[j];
    }
    // ---- colony-specific activation (c uniform per block) ----
    switch (c) {
        case 0:
            #pragma unroll
            for (int j = 0; j < 64; ++j) h[j] = fmaxf(h[j], 0.f);
            break;
        case 1:
            #pragma unroll
            for (int j = 0; j < 64; ++j) h[j] = tanhf(h[j]);
            break;
        case 2:
            #pragma unroll
            for (int j = 0; j < 64; ++j) h[j] = 0.5f * h[j] * (1.f + erff(h[j] * 0.70710678118654752f));
            break;
        case 3:
            #pragma unroll
            for (int j = 0; j < 64; ++j) h[j] = h[j] * sigf(h[j]);
            break;
        case 4:
            #pragma unroll
            for (int j = 0; j < 64; ++j) h[j] = fmaxf(h[j], 0.f) + log1pf(expf(-fabsf(h[j])));
            break;
        case 5:
            #pragma unroll
            for (int j = 0; j < 64; ++j) h[j] = sigf(h[j]);
            break;
        default:
            #pragma unroll
            for (int j = 0; j < 64; ++j) h[j] = fminf(fmaxf(h[j], -1.f), 1.f);
            break;
    }
    // ---- traces = a @ gen_W2[c] + b2, l2norm, store ----
    {
        float t[32];
        const float* bp = gen_b2 + c * 32;
        #pragma unroll
        for (int d = 0; d < 32; ++d) t[d] = bp[d];
        const float* W = gen_W2 + c * 64 * 32;
        #pragma unroll
        for (int j = 0; j < 64; ++j) {
            const float a = h[j];
            const float* w = W + j * 32;
            #pragma unroll
            for (int d = 0; d < 32; ++d) t[d] = fmaf(a, w[d], t[d]);
        }
        float s = 0.f;
        #pragma unroll
        for (int d = 0; d < 32; ++d) s = fmaf(t[d], t[d], s);
        const float inv = 1.f / fmaxf(sqrtf(s), 1e-12f);
        float* op = ws + ((size_t)c * NB + b) * 32;
        #pragma unroll
        for (int d = 0; d < 32; d += 4) {
            float4 o;
            o.x = t[d+0]*inv; o.y = t[d+1]*inv; o.z = t[d+2]*inv; o.w = t[d+3]*inv;
            *(float4*)(op + d) = o;
        }
    }
}

// ============ Kernel B: line gates + comp_conf output ============
// grid = 256 blocks of 256; one thread per batch elem.
__global__ __launch_bounds__(256, 4)
void colB(const float* __restrict__ g_W, const float* __restrict__ g_b,
          float* __restrict__ ws, float* __restrict__ out2)
{
    const int b = blockIdx.x * 256 + threadIdx.x;

    float g[7];
    #pragma unroll
    for (int l = 0; l < 7; ++l) g[l] = g_b[l];

    for (int c = 0; c < 7; ++c) {
        float tv[32];
        const float* tp = ws + ((size_t)c * NB + b) * 32;
        #pragma unroll
        for (int d = 0; d < 32; d += 4) {
            float4 u = *(const float4*)(tp + d);
            tv[d] = u.x; tv[d+1] = u.y; tv[d+2] = u.z; tv[d+3] = u.w;
        }
        #pragma unroll
        for (int k = 0; k < 32; ++k) {
            const float v = tv[k];
            const float* w = g_W + (c * 32 + k) * 7;
            #pragma unroll
            for (int l = 0; l < 7; ++l) g[l] = fmaf(v, w[l], g[l]);
        }
    }
    #pragma unroll
    for (int l = 0; l < 7; ++l) {
        g[l] = sigf(g[l]);
        ws[CF_WS + (size_t)l * NB + b] = g[l];
    }

    float cf[7];
    #pragma unroll
    for (int c = 0; c < 7; ++c) cf[c] = ws[TR_WS + (size_t)c * NB + b];

    float* op = out2 + (size_t)b * 21;
    #pragma unroll
    for (int t = 0; t < 21; ++t) {
        const int l = t / 3;                       // compile-time constants
        const float gl = g[l];
        const float cc = (gl >= 0.3f) ? cf[T_SRC[t]] * cf[T_PAR[t]] * gl : 0.f;
        op[t] = cc;
    }
}

// ============ Kernel C: line composers ============
// grid = 21*256 blocks; block handles task t = blockIdx>>8 for 256 batch elems.
__global__ __launch_bounds__(256, 4)
void colC(const float* __restrict__ c_W1, const float* __restrict__ c_b1,
          const float* __restrict__ c_g,  const float* __restrict__ c_be,
          const float* __restrict__ c_W2, const float* __restrict__ c_b2,
          const float* __restrict__ ws,   float* __restrict__ out)
{
    const int t   = blockIdx.x >> 8;               // uniform
    const int l   = t / 3;                         // uniform
    const int src = T_SRC[t];
    const int par = T_PAR[t];
    const int b   = ((blockIdx.x & 255) << 8) + threadIdx.x;

    const float gate = ws[CF_WS + (size_t)l * NB + b];

    float ch[64];
    {
        const float* bp = c_b1 + l * 64;
        #pragma unroll
        for (int j = 0; j < 64; ++j) ch[j] = bp[j];
    }
    // first half of K: src trace
    {
        float tv[32];
        const float* tp = ws + ((size_t)src * NB + b) * 32;
        #pragma unroll
        for (int d = 0; d < 32; d += 4) {
            float4 u = *(const float4*)(tp + d);
            tv[d] = u.x; tv[d+1] = u.y; tv[d+2] = u.z; tv[d+3] = u.w;
        }
        const float* W = c_W1 + l * 64 * 64;
        for (int i = 0; i < 32; ++i) {
            const float v = tv[i];
            const float* w = W + i * 64;
            #pragma unroll
            for (int j = 0; j < 64; ++j) ch[j] = fmaf(v, w[j], ch[j]);
        }
    }
    // second half of K: partner trace
    {
        float tv[32];
        const float* tp = ws + ((size_t)par * NB + b) * 32;
        #pragma unroll
        for (int d = 0; d < 32; d += 4) {
            float4 u = *(const float4*)(tp + d);
            tv[d] = u.x; tv[d+1] = u.y; tv[d+2] = u.z; tv[d+3] = u.w;
        }
        const float* W = c_W1 + l * 64 * 64 + 32 * 64;
        for (int i = 0; i < 32; ++i) {
            const float v = tv[i];
            const float* w = W + i * 64;
            #pragma unroll
            for (int j = 0; j < 64; ++j) ch[j] = fmaf(v, w[j], ch[j]);
        }
    }
    // LN -> relu
    {
        float m = 0.f;
        #pragma unroll
        for (int j = 0; j < 64; ++j) m += ch[j];
        m *= (1.f / 64.f);
        float v = 0.f;
        #pragma unroll
        for (int j = 0; j < 64; ++j) { float d = ch[j] - m; v = fmaf(d, d, v); }
        v *= (1.f / 64.f);
        const float rs = 1.f / sqrtf(v + 1e-5f);
        const float* gp = c_g  + l * 64;
        const float* bp = c_be + l * 64;
        #pragma unroll
        for (int j = 0; j < 64; ++j) ch[j] = fmaxf((ch[j] - m) * rs * gp[j] + bp[j], 0.f);
    }
    // cv = a @ c_W2[l] + b2
    float cv[32];
    {
        const float* bp = c_b2 + l * 32;
        #pragma unroll
        for (int d = 0; d < 32; ++d) cv[d] = bp[d];
        const float* W2 = c_W2 + l * 64 * 32;
        #pragma unroll
        for (int j = 0; j < 64; ++j) {
            const float a = ch[j];
            const float* w = W2 + j * 32;
            #pragma unroll
            for (int d = 0; d < 32; ++d) cv[d] = fmaf(a, w[d], cv[d]);
        }
    }
    // l2norm + gate + store
    float s = 0.f;
    #pragma unroll
    for (int d = 0; d < 32; ++d) s = fmaf(cv[d], cv[d], s);
    const float inv   = 1.f / fmaxf(sqrtf(s), 1e-12f);
    const float scale = (gate >= 0.3f) ? gate * inv : 0.f;

    float* op = out + (size_t)b * 672 + (size_t)t * 32;
    #pragma unroll
    for (int d = 0; d < 32; d += 4) {
        float4 o;
        o.x = cv[d+0]*scale; o.y = cv[d+1]*scale; o.z = cv[d+2]*scale; o.w = cv[d+3]*scale;
        *(float4*)(op + d) = o;
    }
}

extern "C" void kernel_launch(void* const* d_in, const int* in_sizes, int n_in,
                              void* d_out, int out_size, void* d_ws, size_t ws_size,
                              hipStream_t stream) {
    const float* z      = (const float*)d_in[0];
    const float* gen_W1 = (const float*)d_in[1];
    const float* gen_b1 = (const float*)d_in[2];
    const float* gen_g  = (const float*)d_in[3];
    const float* gen_be = (const float*)d_in[4];
    const float* gen_W2 = (const float*)d_in[5];
    const float* gen_b2 = (const float*)d_in[6];
    const float* cf_W1  = (const float*)d_in[7];
    const float* cf_b1  = (const float*)d_in[8];
    const float* cf_W2  = (const float*)d_in[9];
    const float* cf_b2  = (const float*)d_in[10];
    const float* g_W    = (const float*)d_in[11];
    const float* g_b    = (const float*)d_in[12];
    const float* c_W1   = (const float*)d_in[13];
    const float* c_b1   = (const float*)d_in[14];
    const float* c_g    = (const float*)d_in[15];
    const float* c_be   = (const float*)d_in[16];
    const float* c_W2   = (const float*)d_in[17];
    const float* c_b2   = (const float*)d_in[18];

    float* ws   = (float*)d_ws;
    float* outp = (float*)d_out;
    float* out2 = outp + (size_t)NB * 672;

    colA<<<dim3(7 * 256), dim3(256), 0, stream>>>(
        z, gen_W1, gen_b1, gen_g, gen_be, gen_W2, gen_b2,
        cf_W1, cf_b1, cf_W2, cf_b2, ws);
    colB<<<dim3(256), dim3(256), 0, stream>>>(g_W, g_b, ws, out2);
    colC<<<dim3(21 * 256), dim3(256), 0, stream>>>(
        c_W1, c_b1, c_g, c_be, c_W2, c_b2, ws, outp);
}

// Round 3
// 546.732 us; speedup vs baseline: 2.3078x; 1.3643x over previous
//
#include <hip/hip_runtime.h>
#include <math.h>

#define NB 65536

typedef short s16x8 __attribute__((ext_vector_type(8)));
typedef float f32x4 __attribute__((ext_vector_type(4)));

// ---------------- workspace layout (bytes) ----------------
#define SZ_TR     ((size_t)7*NB*32*2)            // packed bf16 traces (hi or lo)
#define OFF_TRHI  ((size_t)0)
#define OFF_TRLO  (OFF_TRHI + SZ_TR)             // 29,360,128
#define OFF_CONF  (OFF_TRLO + SZ_TR)             // 58,720,256
#define SZ_CONF   ((size_t)7*NB*4)
#define OFF_PART  (OFF_CONF + SZ_CONF)           // 60,555,264
#define SZ_PART   ((size_t)49*NB*4)
#define OFF_GATE  (OFF_PART + SZ_PART)           // 73,400,320
#define SZ_GATE   ((size_t)7*NB*4)
#define OFF_W1H   (OFF_GATE + SZ_GATE)           // weight frags (A-layout, bf16 packed)
#define SZ_W1F    ((size_t)7*4*2*64*16)          // 57,344
#define OFF_W1L   (OFF_W1H + SZ_W1F)
#define OFF_W2H   (OFF_W1L + SZ_W1F)
#define SZ_W2F    ((size_t)7*2*2*64*16)          // 28,672
#define OFF_W2L   (OFF_W2H + SZ_W2F)
// total ~75.4 MB

// task t = l*3+p; src = FANO[l][p], par = FANO[l][(p+1)%3]
static __device__ const int T_SRC[21] = {0,1,2, 0,3,4, 0,5,6, 1,3,5, 1,4,6, 2,3,6, 2,4,5};
static __device__ const int T_PAR[21] = {1,2,0, 3,4,0, 5,6,0, 3,5,1, 4,6,1, 3,6,2, 4,5,2};

__device__ __forceinline__ float sigf(float x) { return 1.f / (1.f + expf(-x)); }

// round-to-nearest-even f32 -> bf16 (as uint16 in low bits)
__device__ __forceinline__ unsigned bfrnd(float x) {
    unsigned u = __builtin_bit_cast(unsigned, x);
    return (u + 0x7FFFu + ((u >> 16) & 1u)) >> 16;
}
__device__ __forceinline__ float bfval(unsigned h) {
    return __builtin_bit_cast(float, h << 16);
}

__device__ __forceinline__ f32x4 mfma16(s16x8 a, s16x8 b, f32x4 c) {
    return __builtin_amdgcn_mfma_f32_16x16x32_bf16(a, b, c, 0, 0, 0);
}

// pack 8 floats -> hi frag + lo frag (bf16 split)
__device__ __forceinline__ void pack8(const float* v, s16x8& hi, s16x8& lo) {
    uint4 hu, lu;
    unsigned h[8], l[8];
    #pragma unroll
    for (int i = 0; i < 8; ++i) {
        h[i] = bfrnd(v[i]);
        float rem = v[i] - bfval(h[i]);
        l[i] = bfrnd(rem);
    }
    hu.x = h[0] | (h[1] << 16); hu.y = h[2] | (h[3] << 16);
    hu.z = h[4] | (h[5] << 16); hu.w = h[6] | (h[7] << 16);
    lu.x = l[0] | (l[1] << 16); lu.y = l[2] | (l[3] << 16);
    lu.z = l[4] | (l[5] << 16); lu.w = l[6] | (l[7] << 16);
    hi = __builtin_bit_cast(s16x8, hu);
    lo = __builtin_bit_cast(s16x8, lu);
}

// ============ Kernel P: swizzle composer weights into MFMA A-fragment order ============
__global__ __launch_bounds__(256, 4)
void colP(const float* __restrict__ c_W1, const float* __restrict__ c_W2,
          uint4* __restrict__ w1h, uint4* __restrict__ w1l,
          uint4* __restrict__ w2h, uint4* __restrict__ w2l)
{
    const int e = blockIdx.x * 256 + threadIdx.x;
    if (e < 3584) {                       // W1 frags: [(l*4+mt)*2+ks][lane]
        const int lane = e & 63, er = e >> 6;
        const int ks = er & 1, mt = (er >> 1) & 3, l = er >> 3;
        const int j  = mt * 16 + (lane & 15);          // A row m = output feature
        const int k0 = ks * 32 + (lane >> 4) * 8;      // A col k = input (pair) dim
        float v[8];
        #pragma unroll
        for (int jj = 0; jj < 8; ++jj) v[jj] = c_W1[((size_t)(l * 64 + k0 + jj)) * 64 + j];
        s16x8 hi, lo; pack8(v, hi, lo);
        w1h[e] = __builtin_bit_cast(uint4, hi);
        w1l[e] = __builtin_bit_cast(uint4, lo);
    } else if (e < 5376) {                // W2 frags: [(l*2+mt2)*2+ks2][lane]
        const int e2 = e - 3584;
        const int lane = e2 & 63, er = e2 >> 6;
        const int ks2 = er & 1, mt2 = (er >> 1) & 1, l = er >> 2;
        const int d  = mt2 * 16 + (lane & 15);
        const int k0 = ks2 * 32 + (lane >> 4) * 8;
        float v[8];
        #pragma unroll
        for (int jj = 0; jj < 8; ++jj) v[jj] = c_W2[((size_t)(l * 64 + k0 + jj)) * 32 + d];
        s16x8 hi, lo; pack8(v, hi, lo);
        w2h[e2] = __builtin_bit_cast(uint4, hi);
        w2l[e2] = __builtin_bit_cast(uint4, lo);
    }
}

// ============ Kernel A: per-colony trace generator + confidence + gate partials ============
__global__ __launch_bounds__(256, 4)
void colA(const float* __restrict__ z,
          const float* __restrict__ gen_W1, const float* __restrict__ gen_b1,
          const float* __restrict__ gen_g,  const float* __restrict__ gen_be,
          const float* __restrict__ gen_W2, const float* __restrict__ gen_b2,
          const float* __restrict__ cf_W1,  const float* __restrict__ cf_b1,
          const float* __restrict__ cf_W2,  const float* __restrict__ cf_b2,
          const float* __restrict__ g_W,
          uint4* __restrict__ trHI, uint4* __restrict__ trLO,
          float* __restrict__ conf, float* __restrict__ part)
{
    const int c = blockIdx.x >> 8;
    const int b = ((blockIdx.x & 255) << 8) + threadIdx.x;

    float zv[14];
    {
        const float* zp = z + ((size_t)b * 7 + (size_t)c) * 14;
        #pragma unroll
        for (int i = 0; i < 7; ++i) {
            float2 u = *(const float2*)(zp + 2 * i);
            zv[2*i] = u.x; zv[2*i+1] = u.y;
        }
    }

    // ---- confidence head ----
    {
        float hc[32];
        const float* bp = cf_b1 + c * 32;
        #pragma unroll
        for (int k = 0; k < 32; ++k) hc[k] = bp[k];
        const float* W = cf_W1 + c * 14 * 32;
        for (int i = 0; i < 14; ++i) {
            const float zi = zv[i];
            const float* w = W + i * 32;
            #pragma unroll
            for (int k = 0; k < 32; ++k) hc[k] = fmaf(zi, w[k], hc[k]);
        }
        float cl = cf_b2[c];
        const float* w2 = cf_W2 + c * 32;
        #pragma unroll
        for (int k = 0; k < 32; ++k) cl = fmaf(fmaxf(hc[k], 0.f), w2[k], cl);
        conf[(size_t)c * NB + b] = sigf(cl);
    }

    // ---- h = z @ gen_W1[c] + b1 ----
    float h[64];
    {
        const float* bp = gen_b1 + c * 64;
        #pragma unroll
        for (int j = 0; j < 64; ++j) h[j] = bp[j];
        const float* W = gen_W1 + c * 14 * 64;
        for (int i = 0; i < 14; ++i) {
            const float zi = zv[i];
            const float* w = W + i * 64;
            #pragma unroll
            for (int j = 0; j < 64; ++j) h[j] = fmaf(zi, w[j], h[j]);
        }
    }
    // ---- LayerNorm ----
    {
        float m = 0.f;
        #pragma unroll
        for (int j = 0; j < 64; ++j) m += h[j];
        m *= (1.f / 64.f);
        float v = 0.f;
        #pragma unroll
        for (int j = 0; j < 64; ++j) { float d = h[j] - m; v = fmaf(d, d, v); }
        v *= (1.f / 64.f);
        const float rs = 1.f / sqrtf(v + 1e-5f);
        const float* gp = gen_g  + c * 64;
        const float* bp = gen_be + c * 64;
        #pragma unroll
        for (int j = 0; j < 64; ++j) h[j] = (h[j] - m) * rs * gp[j] + bp[j];
    }
    // ---- colony-specific activation ----
    switch (c) {
        case 0:
            #pragma unroll
            for (int j = 0; j < 64; ++j) h[j] = fmaxf(h[j], 0.f);
            break;
        case 1:
            #pragma unroll
            for (int j = 0; j < 64; ++j) h[j] = tanhf(h[j]);
            break;
        case 2:
            #pragma unroll
            for (int j = 0; j < 64; ++j) h[j] = 0.5f * h[j] * (1.f + erff(h[j] * 0.70710678118654752f));
            break;
        case 3:
            #pragma unroll
            for (int j = 0; j < 64; ++j) h[j] = h[j] * sigf(h[j]);
            break;
        case 4:
            #pragma unroll
            for (int j = 0; j < 64; ++j) h[j] = fmaxf(h[j], 0.f) + log1pf(expf(-fabsf(h[j])));
            break;
        case 5:
            #pragma unroll
            for (int j = 0; j < 64; ++j) h[j] = sigf(h[j]);
            break;
        default:
            #pragma unroll
            for (int j = 0; j < 64; ++j) h[j] = fminf(fmaxf(h[j], -1.f), 1.f);
            break;
    }
    // ---- traces = a @ gen_W2[c] + b2, l2norm ----
    float tn[32];
    {
        float t[32];
        const float* bp = gen_b2 + c * 32;
        #pragma unroll
        for (int d = 0; d < 32; ++d) t[d] = bp[d];
        const float* W = gen_W2 + c * 64 * 32;
        #pragma unroll
        for (int j = 0; j < 64; ++j) {
            const float a = h[j];
            const float* w = W + j * 32;
            #pragma unroll
            for (int d = 0; d < 32; ++d) t[d] = fmaf(a, w[d], t[d]);
        }
        float s = 0.f;
        #pragma unroll
        for (int d = 0; d < 32; ++d) s = fmaf(t[d], t[d], s);
        const float inv = 1.f / fmaxf(sqrtf(s), 1e-12f);
        #pragma unroll
        for (int d = 0; d < 32; ++d) tn[d] = t[d] * inv;
    }
    // ---- packed bf16 hi/lo trace store (for colC MFMA B-frags) ----
    {
        unsigned hw[16], lw[16];
        #pragma unroll
        for (int i = 0; i < 16; ++i) {
            unsigned h0 = bfrnd(tn[2*i]),   h1 = bfrnd(tn[2*i+1]);
            float r0 = tn[2*i]   - bfval(h0);
            float r1 = tn[2*i+1] - bfval(h1);
            hw[i] = h0 | (h1 << 16);
            lw[i] = bfrnd(r0) | (bfrnd(r1) << 16);
        }
        const size_t base = ((size_t)c * NB + b) * 4;
        #pragma unroll
        for (int k = 0; k < 4; ++k) {
            uint4 u; u.x = hw[4*k]; u.y = hw[4*k+1]; u.z = hw[4*k+2]; u.w = hw[4*k+3];
            trHI[base + k] = u;
            uint4 v; v.x = lw[4*k]; v.y = lw[4*k+1]; v.z = lw[4*k+2]; v.w = lw[4*k+3];
            trLO[base + k] = v;
        }
    }
    // ---- gate partials: p[l2] = sum_k tn[k] * g_W[(c*32+k)*7 + l2] ----
    {
        float p[7] = {0.f,0.f,0.f,0.f,0.f,0.f,0.f};
        for (int k = 0; k < 32; ++k) {
            const float v = tn[k];
            const float* w = g_W + (c * 32 + k) * 7;
            #pragma unroll
            for (int l2 = 0; l2 < 7; ++l2) p[l2] = fmaf(v, w[l2], p[l2]);
        }
        #pragma unroll
        for (int l2 = 0; l2 < 7; ++l2) part[((size_t)(c * 7 + l2)) * NB + b] = p[l2];
    }
}

// ============ Kernel B: gates + comp_conf output ============
__global__ __launch_bounds__(256, 4)
void colB(const float* __restrict__ g_b,
          const float* __restrict__ part, const float* __restrict__ conf,
          float* __restrict__ gates, float* __restrict__ out2)
{
    const int b = blockIdx.x * 256 + threadIdx.x;

    float g[7];
    #pragma unroll
    for (int l = 0; l < 7; ++l) g[l] = g_b[l];
    for (int c = 0; c < 7; ++c) {
        #pragma unroll
        for (int l = 0; l < 7; ++l) g[l] += part[((size_t)(c * 7 + l)) * NB + b];
    }
    #pragma unroll
    for (int l = 0; l < 7; ++l) {
        g[l] = sigf(g[l]);
        gates[(size_t)l * NB + b] = g[l];
    }

    float cf[7];
    #pragma unroll
    for (int c = 0; c < 7; ++c) cf[c] = conf[(size_t)c * NB + b];

    float* op = out2 + (size_t)b * 21;
    #pragma unroll
    for (int t = 0; t < 21; ++t) {
        const int l = t / 3;
        const float gl = g[l];
        op[t] = (gl >= 0.3f) ? cf[T_SRC[t]] * cf[T_PAR[t]] * gl : 0.f;
    }
}

// ============ Kernel C: composers via split-bf16 MFMA ============
// 64 blocks per task; block = 4 waves; wave handles 16 tiles x 16 batch = 256 batch.
__global__ __launch_bounds__(256, 2)
void colC(const uint4* __restrict__ trHI, const uint4* __restrict__ trLO,
          const float* __restrict__ gates,
          const uint4* __restrict__ w1fh, const uint4* __restrict__ w1fl,
          const uint4* __restrict__ w2fh, const uint4* __restrict__ w2fl,
          const float* __restrict__ c_b1,
          const float* __restrict__ c_g,  const float* __restrict__ c_be,
          const float* __restrict__ c_b2, float* __restrict__ out)
{
    __shared__ float lds[4][16 * 68];   // per-wave CH^T buffer [b][j], stride 68 (pad)

    const int wave = threadIdx.x >> 6;
    const int lane = threadIdx.x & 63;
    const int q    = lane >> 4;         // quad
    const int bl   = lane & 15;         // batch-in-tile (MFMA column)

    const int t   = blockIdx.x >> 6;    // 64 blocks per task
    const int l   = t / 3;
    const int src = T_SRC[t];
    const int par = T_PAR[t];
    const int base = ((blockIdx.x & 63) << 10) + (wave << 8);   // wave's batch base

    // ---- per-task weight fragments (live across all 16 tiles) ----
    s16x8 w1h[4][2], w1l[4][2], w2h[2][2], w2l[2][2];
    #pragma unroll
    for (int mt = 0; mt < 4; ++mt)
        #pragma unroll
        for (int ks = 0; ks < 2; ++ks) {
            w1h[mt][ks] = __builtin_bit_cast(s16x8, w1fh[((l * 4 + mt) * 2 + ks) * 64 + lane]);
            w1l[mt][ks] = __builtin_bit_cast(s16x8, w1fl[((l * 4 + mt) * 2 + ks) * 64 + lane]);
        }
    #pragma unroll
    for (int mt = 0; mt < 2; ++mt)
        #pragma unroll
        for (int ks = 0; ks < 2; ++ks) {
            w2h[mt][ks] = __builtin_bit_cast(s16x8, w2fh[((l * 2 + mt) * 2 + ks) * 64 + lane]);
            w2l[mt][ks] = __builtin_bit_cast(s16x8, w2fl[((l * 2 + mt) * 2 + ks) * 64 + lane]);
        }

    // ---- per-task LN/bias params: lane covers j = 16*mt + 4*q + (0..3) ----
    f32x4 b1v[4], gv[4], bev[4], b2v[2];
    {
        const f32x4* p1 = (const f32x4*)(c_b1 + (size_t)l * 64);
        const f32x4* pg = (const f32x4*)(c_g  + (size_t)l * 64);
        const f32x4* pb = (const f32x4*)(c_be + (size_t)l * 64);
        #pragma unroll
        for (int mt = 0; mt < 4; ++mt) {
            b1v[mt] = p1[4 * mt + q]; gv[mt] = pg[4 * mt + q]; bev[mt] = pb[4 * mt + q];
        }
        const f32x4* p2 = (const f32x4*)(c_b2 + (size_t)l * 32);
        #pragma unroll
        for (int mt = 0; mt < 2; ++mt) b2v[mt] = p2[4 * mt + q];
    }

    float* ldsw = &lds[wave][0];

    for (int it = 0; it < 16; ++it) {
        const int bg = base + it * 16 + bl;     // global batch elem for this column

        // trace B-frags: lane holds PairIn[bg][k], k = 8q+jj (src half / par half)
        const size_t sb = ((size_t)src * NB + bg) * 4 + q;
        const size_t pb = ((size_t)par * NB + bg) * 4 + q;
        s16x8 bsh = __builtin_bit_cast(s16x8, trHI[sb]);
        s16x8 bsl = __builtin_bit_cast(s16x8, trLO[sb]);
        s16x8 bph = __builtin_bit_cast(s16x8, trHI[pb]);
        s16x8 bpl = __builtin_bit_cast(s16x8, trLO[pb]);
        const float gate = gates[(size_t)l * NB + bg];

        // ---- GEMM1: CH^T[j][b] = W1^T @ PairIn^T  (split-3) ----
        f32x4 acc[4];
        #pragma unroll
        for (int mt = 0; mt < 4; ++mt) {
            f32x4 a = {0.f, 0.f, 0.f, 0.f};
            a = mfma16(w1h[mt][0], bsh, a);
            a = mfma16(w1h[mt][0], bsl, a);
            a = mfma16(w1l[mt][0], bsh, a);
            a = mfma16(w1h[mt][1], bph, a);
            a = mfma16(w1h[mt][1], bpl, a);
            a = mfma16(w1l[mt][1], bph, a);
            acc[mt] = a;
        }
        // + bias
        #pragma unroll
        for (int mt = 0; mt < 4; ++mt) acc[mt] += b1v[mt];

        // ---- LayerNorm over 64 features (16 lane-local + quad butterfly) ----
        float s = 0.f;
        #pragma unroll
        for (int mt = 0; mt < 4; ++mt)
            #pragma unroll
            for (int r = 0; r < 4; ++r) s += acc[mt][r];
        s += __shfl_xor(s, 16);
        s += __shfl_xor(s, 32);
        const float mean = s * (1.f / 64.f);
        float v = 0.f;
        #pragma unroll
        for (int mt = 0; mt < 4; ++mt)
            #pragma unroll
            for (int r = 0; r < 4; ++r) { float d = acc[mt][r] - mean; v = fmaf(d, d, v); }
        v += __shfl_xor(v, 16);
        v += __shfl_xor(v, 32);
        const float rs = 1.f / sqrtf(v * (1.f / 64.f) + 1e-5f);

        // normalize + affine + relu, stash to per-wave LDS [b][j]
        #pragma unroll
        for (int mt = 0; mt < 4; ++mt) {
            f32x4 x;
            #pragma unroll
            for (int r = 0; r < 4; ++r)
                x[r] = fmaxf(fmaf((acc[mt][r] - mean) * rs, gv[mt][r], bev[mt][r]), 0.f);
            *(f32x4*)&ldsw[bl * 68 + 16 * mt + 4 * q] = x;
        }

        // ---- GEMM2: CV^T[d][b] = W2^T @ CH ----
        f32x4 d0 = {0.f,0.f,0.f,0.f}, d1 = {0.f,0.f,0.f,0.f};
        #pragma unroll
        for (int ks2 = 0; ks2 < 2; ++ks2) {
            // lane needs CH[j = 32*ks2 + 8q + jj][bl]
            f32x4 c0 = *(const f32x4*)&ldsw[bl * 68 + 32 * ks2 + 8 * q];
            f32x4 c1 = *(const f32x4*)&ldsw[bl * 68 + 32 * ks2 + 8 * q + 4];
            float vv[8] = {c0[0], c0[1], c0[2], c0[3], c1[0], c1[1], c1[2], c1[3]};
            s16x8 chh, chl; pack8(vv, chh, chl);
            d0 = mfma16(w2h[0][ks2], chh, d0);
            d0 = mfma16(w2h[0][ks2], chl, d0);
            d0 = mfma16(w2l[0][ks2], chh, d0);
            d1 = mfma16(w2h[1][ks2], chh, d1);
            d1 = mfma16(w2h[1][ks2], chl, d1);
            d1 = mfma16(w2l[1][ks2], chh, d1);
        }
        d0 += b2v[0];
        d1 += b2v[1];

        // ---- l2norm over 32 d's + gate + store ----
        float ss = 0.f;
        #pragma unroll
        for (int r = 0; r < 4; ++r) { ss = fmaf(d0[r], d0[r], ss); ss = fmaf(d1[r], d1[r], ss); }
        ss += __shfl_xor(ss, 16);
        ss += __shfl_xor(ss, 32);
        const float inv   = 1.f / fmaxf(sqrtf(ss), 1e-12f);
        const float scale = (gate >= 0.3f) ? gate * inv : 0.f;

        float* op = out + (size_t)bg * 672 + t * 32;
        f32x4 o0, o1;
        #pragma unroll
        for (int r = 0; r < 4; ++r) { o0[r] = d0[r] * scale; o1[r] = d1[r] * scale; }
        *(f32x4*)(op + 4 * q)      = o0;   // d = 4q + r      (mt2 = 0)
        *(f32x4*)(op + 16 + 4 * q) = o1;   // d = 16 + 4q + r (mt2 = 1)
    }
}

extern "C" void kernel_launch(void* const* d_in, const int* in_sizes, int n_in,
                              void* d_out, int out_size, void* d_ws, size_t ws_size,
                              hipStream_t stream) {
    const float* z      = (const float*)d_in[0];
    const float* gen_W1 = (const float*)d_in[1];
    const float* gen_b1 = (const float*)d_in[2];
    const float* gen_g  = (const float*)d_in[3];
    const float* gen_be = (const float*)d_in[4];
    const float* gen_W2 = (const float*)d_in[5];
    const float* gen_b2 = (const float*)d_in[6];
    const float* cf_W1  = (const float*)d_in[7];
    const float* cf_b1  = (const float*)d_in[8];
    const float* cf_W2  = (const float*)d_in[9];
    const float* cf_b2  = (const float*)d_in[10];
    const float* g_W    = (const float*)d_in[11];
    const float* g_b    = (const float*)d_in[12];
    const float* c_W1   = (const float*)d_in[13];
    const float* c_b1   = (const float*)d_in[14];
    const float* c_g    = (const float*)d_in[15];
    const float* c_be   = (const float*)d_in[16];
    const float* c_W2   = (const float*)d_in[17];
    const float* c_b2   = (const float*)d_in[18];

    char* wsb = (char*)d_ws;
    uint4* trHI  = (uint4*)(wsb + OFF_TRHI);
    uint4* trLO  = (uint4*)(wsb + OFF_TRLO);
    float* conf  = (float*)(wsb + OFF_CONF);
    float* part  = (float*)(wsb + OFF_PART);
    float* gates = (float*)(wsb + OFF_GATE);
    uint4* w1fh  = (uint4*)(wsb + OFF_W1H);
    uint4* w1fl  = (uint4*)(wsb + OFF_W1L);
    uint4* w2fh  = (uint4*)(wsb + OFF_W2H);
    uint4* w2fl  = (uint4*)(wsb + OFF_W2L);

    float* outp = (float*)d_out;
    float* out2 = outp + (size_t)NB * 672;

    colP<<<dim3(21), dim3(256), 0, stream>>>(c_W1, c_W2, w1fh, w1fl, w2fh, w2fl);
    colA<<<dim3(7 * 256), dim3(256), 0, stream>>>(
        z, gen_W1, gen_b1, gen_g, gen_be, gen_W2, gen_b2,
        cf_W1, cf_b1, cf_W2, cf_b2, g_W, trHI, trLO, conf, part);
    colB<<<dim3(256), dim3(256), 0, stream>>>(g_b, part, conf, gates, out2);
    colC<<<dim3(21 * 64), dim3(256), 0, stream>>>(
        trHI, trLO, gates, w1fh, w1fl, w2fh, w2fl,
        c_b1, c_g, c_be, c_b2, outp);
}